// Round 5
// baseline (312.729 us; speedup 1.0000x reference)
//
#include <hip/hip_runtime.h>
#include <hip/hip_bf16.h>

typedef __bf16 bf16x8 __attribute__((ext_vector_type(8)));
typedef __bf16 bf16x4 __attribute__((ext_vector_type(4)));
typedef float  f32x4  __attribute__((ext_vector_type(4)));

// ---------------- workspace layout (bytes) ----------------
static constexpr size_t MB = 1u << 20;
static constexpr size_t HI_OFF  = 0;                       // 2048*128*4 = 1 MiB
static constexpr size_t HJ_OFF  = HI_OFF + MB;
static constexpr size_t HIS_OFF = HJ_OFF + MB;             // a1*hi
static constexpr size_t QV_OFF  = HIS_OFF + MB;            // a1*hj + d1
static constexpr size_t Z_OFF   = QV_OFF + MB;             // 524288*128*2 = 128 MiB (z2 only)
static constexpr size_t PS_OFF  = Z_OFF + (size_t)524288 * 128 * 2;   // 4096*128*4 = 2 MiB
static constexpr size_t PQ_OFF  = PS_OFF + (size_t)4096 * 128 * 4;
static constexpr size_t S1I_OFF = PQ_OFF + (size_t)4096 * 128 * 4;    // 64*128*4 = 32 KiB each
static constexpr size_t S2I_OFF = S1I_OFF + 32768;
static constexpr size_t S1J_OFF = S2I_OFF + 32768;
static constexpr size_t S2J_OFF = S1J_OFF + 32768;
static constexpr size_t A1_OFF  = S2J_OFF + 32768;         // 128*4 = 512 each
static constexpr size_t D1_OFF  = A1_OFF + 512;
static constexpr size_t A2_OFF  = D1_OFF + 512;
static constexpr size_t C2_OFF  = A2_OFF + 512;
static constexpr size_t A3_OFF  = C2_OFF + 512;
static constexpr size_t C3_OFF  = A3_OFF + 512;
static constexpr size_t AF_OFF  = C3_OFF + 512;
static constexpr size_t CF_OFF  = AF_OFF + 512;
static constexpr size_t AO_OFF  = CF_OFF + 512;
static constexpr size_t CO_OFF  = AO_OFF + 512;
static constexpr size_t W2T_OFF = CO_OFF + 512;            // 128*128*2 = 32 KiB
static constexpr size_t W3T_OFF = W2T_OFF + 32768;
static constexpr size_t XAGG_OFF = W3T_OFF + 32768;        // 1 MiB
static constexpr size_t Y1_OFF  = XAGG_OFF + MB;
static constexpr size_t Y2_OFF  = Y1_OFF + MB;
static constexpr size_t TPS_OFF = Y2_OFF + MB;             // 64 KiB
static constexpr size_t TPQ_OFF = TPS_OFF + 65536;

// ---------------- K1: hi = xf@W1a, hj = xf@W1b ----------------
__global__ void build_h(const float* __restrict__ x, const float* __restrict__ coord,
                        const float* __restrict__ W1a, const float* __restrict__ W1b,
                        float* __restrict__ hi, float* __restrict__ hj)
{
    __shared__ float xr[18];
    int bl = blockIdx.x;            // b*256 + l
    int b = bl >> 8, l = bl & 255;
    int t = threadIdx.x;            // 128 = channel f
    if (t < 18)
        xr[t] = (t < 16) ? x[((size_t)b * 16 + t) * 256 + l] : coord[l * 2 + (t - 16)];
    __syncthreads();
    float ai = 0.f, aj = 0.f;
#pragma unroll
    for (int c = 0; c < 18; ++c) {
        float xv = xr[c];
        ai += xv * W1a[c * 128 + t];
        aj += xv * W1b[c * 128 + t];
    }
    hi[(size_t)bl * 128 + t] = ai;
    hj[(size_t)bl * 128 + t] = aj;
}

// ---------------- K2: per-(b,lgroup) moments of hi/hj ----------------
__global__ void stats1(const float* __restrict__ hi, const float* __restrict__ hj,
                       float* __restrict__ S1i, float* __restrict__ S2i,
                       float* __restrict__ S1j, float* __restrict__ S2j)
{
    int g = blockIdx.x;             // b*8 + lg
    int b = g >> 3, lg = g & 7;
    int f = threadIdx.x;
    float s1i = 0, s2i = 0, s1j = 0, s2j = 0;
#pragma unroll 4
    for (int i = 0; i < 32; ++i) {
        int l = lg * 32 + i;
        float vi = hi[((size_t)b * 256 + l) * 128 + f];
        float vj = hj[((size_t)b * 256 + l) * 128 + f];
        s1i += vi; s2i += vi * vi;
        s1j += vj; s2j += vj * vj;
    }
    S1i[g * 128 + f] = s1i; S2i[g * 128 + f] = s2i;
    S1j[g * 128 + f] = s1j; S2j[g * 128 + f] = s2j;
}

// ---------------- K2b: BN1 closed-form ----------------
__global__ void bn1_finalize(const float* __restrict__ S1i, const float* __restrict__ S2i,
                             const float* __restrict__ S1j, const float* __restrict__ S2j,
                             const float* __restrict__ g, const float* __restrict__ be,
                             float* __restrict__ a1, float* __restrict__ d1)
{
    int f = threadIdx.x;  // 128
    float s1i = 0, s2i = 0, s1j = 0, s2j = 0;
    float mib[8], mjb[8];
#pragma unroll
    for (int b = 0; b < 8; ++b) {
        float sb = 0, sbj = 0;
#pragma unroll
        for (int lg = 0; lg < 8; ++lg) {
            int gg = b * 8 + lg;
            sb  += S1i[gg * 128 + f]; s2i += S2i[gg * 128 + f];
            sbj += S1j[gg * 128 + f]; s2j += S2j[gg * 128 + f];
        }
        mib[b] = sb * (1.f / 256.f); mjb[b] = sbj * (1.f / 256.f);
        s1i += sb; s1j += sbj;
    }
    const float invN = 1.f / 2048.f;
    float mi = s1i * invN, mj = s1j * invN;
    float vu = s2i * invN - mi * mi;
    float vv = s2j * invN - mj * mj;
    float cr = 0.f;
#pragma unroll
    for (int b = 0; b < 8; ++b) cr += (mib[b] - mi) * (mjb[b] - mj);
    cr *= (1.f / 8.f);
    float var = vu + vv + 2.f * cr;
    float av = g[f] * rsqrtf(var + 1e-5f);
    a1[f] = av;
    d1[f] = be[f] - av * (mi + mj);   // b1 cancels (BN shift invariance)
}

// ---------------- transposed bf16 weights ----------------
__global__ void transpose_w(const float* __restrict__ W2, const float* __restrict__ W3,
                            __bf16* __restrict__ W2t, __bf16* __restrict__ W3t)
{
    int f = blockIdx.x, k = threadIdx.x;   // Wt[f][k] = W[k][f]
    W2t[f * 128 + k] = (__bf16)W2[k * 128 + f];
    W3t[f * 128 + k] = (__bf16)W3[k * 128 + f];
}

// ---------------- fold BN1 scale into hi/hj ----------------
__global__ void scale_h(const float* __restrict__ hi, const float* __restrict__ hj,
                        const float* __restrict__ a1, const float* __restrict__ d1,
                        float* __restrict__ his, float* __restrict__ qv)
{
    int bl = blockIdx.x, f = threadIdx.x;
    float a = a1[f];
    his[(size_t)bl * 128 + f] = a * hi[(size_t)bl * 128 + f];
    qv[(size_t)bl * 128 + f]  = a * hj[(size_t)bl * 128 + f] + d1[f];
}

// ============ P1: z2 = relu(his[l] + qv[k]) @ W2, + BN2 partial stats ============
// grid 4096 x 256thr. Block = 128 l-rows of one (b,k) band; wave = 32 rows x 128 cols.
// A-fragments built directly in registers from L2-resident his/qv. No barriers in hot path.
__global__ __launch_bounds__(256) void pair_stage1(
    const float* __restrict__ HIS, const float* __restrict__ QV,
    const __bf16* __restrict__ W2t, __bf16* __restrict__ Z,
    float* __restrict__ ps, float* __restrict__ pq)
{
    __shared__ __align__(16) char wlds[32768];
    __shared__ float red[2][4][128];

    int blk = blockIdx.x;
    int bk = blk >> 1, half = blk & 1;
    int b  = bk >> 8;
    int t = threadIdx.x, lane = t & 63, wave = t >> 6;
    int cl = lane & 15, kg = lane >> 4;

    {   // one-time W stage (XOR-swizzled)
        int fcs = t & 15, rs = t >> 4;
#pragma unroll
        for (int i = 0; i < 8; ++i) {
            int row = rs + i * 16;
            bf16x8 w = *reinterpret_cast<const bf16x8*>(W2t + row * 128 + fcs * 8);
            int byte = row * 256 + ((fcs * 16) ^ ((row & 7) << 4));
            *reinterpret_cast<bf16x8*>(wlds + byte) = w;
        }
    }
    __syncthreads();

    int lrow0 = half * 128 + wave * 32;                 // l within band (0..255)
    size_t zrow0 = (size_t)bk * 256 + lrow0;            // row in pair space
    const float* qvp = QV + (size_t)bk * 128;

    f32x4 acc[2][8] = {};
#pragma unroll
    for (int kk = 0; kk < 4; ++kk) {
        int ko = kk * 32 + kg * 8;
        f32x4 q0 = *reinterpret_cast<const f32x4*>(qvp + ko);
        f32x4 q1 = *reinterpret_cast<const f32x4*>(qvp + ko + 4);
        bf16x8 Af[2];
#pragma unroll
        for (int m = 0; m < 2; ++m) {
            const float* hp = HIS + ((size_t)(b * 256 + lrow0 + m * 16 + cl)) * 128 + ko;
            f32x4 h0 = *reinterpret_cast<const f32x4*>(hp);
            f32x4 h1 = *reinterpret_cast<const f32x4*>(hp + 4);
#pragma unroll
            for (int j = 0; j < 4; ++j) {
                Af[m][j]     = (__bf16)fmaxf(h0[j] + q0[j], 0.f);
                Af[m][j + 4] = (__bf16)fmaxf(h1[j] + q1[j], 0.f);
            }
        }
#pragma unroll
        for (int n = 0; n < 8; ++n) {
            int r = n * 16 + cl;
            int byte = r * 256 + (((kk * 4 + kg) * 16) ^ ((cl & 7) << 4));
            bf16x8 Bf = *reinterpret_cast<const bf16x8*>(wlds + byte);
#pragma unroll
            for (int m = 0; m < 2; ++m)
                acc[m][n] = __builtin_amdgcn_mfma_f32_16x16x32_bf16(Bf, Af[m], acc[m][n], 0, 0, 0);
        }
    }

    // store z2 (8B packed) + per-channel partial stats
#pragma unroll
    for (int n = 0; n < 8; ++n) {
        float sv[4], q2[4];
#pragma unroll
        for (int m = 0; m < 2; ++m) {
            bf16x4 pv;
#pragma unroll
            for (int r = 0; r < 4; ++r) {
                float v = acc[m][n][r];
                pv[r] = (__bf16)v;
                if (m == 0) { sv[r] = v;  q2[r] = v * v; }
                else        { sv[r] += v; q2[r] += v * v; }
            }
            *reinterpret_cast<bf16x4*>(Z + (zrow0 + m * 16 + cl) * 128 + n * 16 + kg * 4) = pv;
        }
#pragma unroll
        for (int r = 0; r < 4; ++r) {
            sv[r] += __shfl_xor(sv[r], 1); sv[r] += __shfl_xor(sv[r], 2);
            sv[r] += __shfl_xor(sv[r], 4); sv[r] += __shfl_xor(sv[r], 8);
            q2[r] += __shfl_xor(q2[r], 1); q2[r] += __shfl_xor(q2[r], 2);
            q2[r] += __shfl_xor(q2[r], 4); q2[r] += __shfl_xor(q2[r], 8);
        }
        if (cl == 0) {
#pragma unroll
            for (int r = 0; r < 4; ++r) {
                red[0][wave][n * 16 + kg * 4 + r] = sv[r];
                red[1][wave][n * 16 + kg * 4 + r] = q2[r];
            }
        }
    }
    __syncthreads();
    if (t < 128) {
        ps[(size_t)blk * 128 + t] = red[0][0][t] + red[0][1][t] + red[0][2][t] + red[0][3][t];
        pq[(size_t)blk * 128 + t] = red[1][0][t] + red[1][1][t] + red[1][2][t] + red[1][3][t];
    }
}

// ============ P2: z3 stats. reads z2, z3 = relu(a2*z2+c2) @ W3, accumulate BN3 stats only ============
__global__ __launch_bounds__(256) void pair_stage2(
    const __bf16* __restrict__ Z,
    const float* __restrict__ a2, const float* __restrict__ c2,
    const __bf16* __restrict__ W3t,
    float* __restrict__ ps, float* __restrict__ pq)
{
    __shared__ __align__(16) char wlds[32768];
    __shared__ float red[2][4][128];

    int blk = blockIdx.x;
    int bk = blk >> 1, half = blk & 1;
    int t = threadIdx.x, lane = t & 63, wave = t >> 6;
    int cl = lane & 15, kg = lane >> 4;

    {
        int fcs = t & 15, rs = t >> 4;
#pragma unroll
        for (int i = 0; i < 8; ++i) {
            int row = rs + i * 16;
            bf16x8 w = *reinterpret_cast<const bf16x8*>(W3t + row * 128 + fcs * 8);
            int byte = row * 256 + ((fcs * 16) ^ ((row & 7) << 4));
            *reinterpret_cast<bf16x8*>(wlds + byte) = w;
        }
    }
    __syncthreads();

    size_t row0 = (size_t)bk * 256 + half * 128 + wave * 32;

    f32x4 acc[2][8] = {};
#pragma unroll
    for (int kk = 0; kk < 4; ++kk) {
        int ko = kk * 32 + kg * 8;
        f32x4 a2l = *reinterpret_cast<const f32x4*>(a2 + ko);
        f32x4 a2h = *reinterpret_cast<const f32x4*>(a2 + ko + 4);
        f32x4 c2l = *reinterpret_cast<const f32x4*>(c2 + ko);
        f32x4 c2h = *reinterpret_cast<const f32x4*>(c2 + ko + 4);
        bf16x8 Af[2];
#pragma unroll
        for (int m = 0; m < 2; ++m) {
            bf16x8 zv = *reinterpret_cast<const bf16x8*>(Z + (row0 + m * 16 + cl) * 128 + ko);
#pragma unroll
            for (int j = 0; j < 4; ++j) {
                Af[m][j]     = (__bf16)fmaxf(a2l[j] * (float)zv[j] + c2l[j], 0.f);
                Af[m][j + 4] = (__bf16)fmaxf(a2h[j] * (float)zv[j + 4] + c2h[j], 0.f);
            }
        }
#pragma unroll
        for (int n = 0; n < 8; ++n) {
            int r = n * 16 + cl;
            int byte = r * 256 + (((kk * 4 + kg) * 16) ^ ((cl & 7) << 4));
            bf16x8 Bf = *reinterpret_cast<const bf16x8*>(wlds + byte);
#pragma unroll
            for (int m = 0; m < 2; ++m)
                acc[m][n] = __builtin_amdgcn_mfma_f32_16x16x32_bf16(Bf, Af[m], acc[m][n], 0, 0, 0);
        }
    }

#pragma unroll
    for (int n = 0; n < 8; ++n) {
        float sv[4], q2[4];
#pragma unroll
        for (int r = 0; r < 4; ++r) {
            float v0 = acc[0][n][r], v1 = acc[1][n][r];
            sv[r] = v0 + v1; q2[r] = v0 * v0 + v1 * v1;
            sv[r] += __shfl_xor(sv[r], 1); sv[r] += __shfl_xor(sv[r], 2);
            sv[r] += __shfl_xor(sv[r], 4); sv[r] += __shfl_xor(sv[r], 8);
            q2[r] += __shfl_xor(q2[r], 1); q2[r] += __shfl_xor(q2[r], 2);
            q2[r] += __shfl_xor(q2[r], 4); q2[r] += __shfl_xor(q2[r], 8);
        }
        if (cl == 0) {
#pragma unroll
            for (int r = 0; r < 4; ++r) {
                red[0][wave][n * 16 + kg * 4 + r] = sv[r];
                red[1][wave][n * 16 + kg * 4 + r] = q2[r];
            }
        }
    }
    __syncthreads();
    if (t < 128) {
        ps[(size_t)blk * 128 + t] = red[0][0][t] + red[0][1][t] + red[0][2][t] + red[0][3][t];
        pq[(size_t)blk * 128 + t] = red[1][0][t] + red[1][1][t] + red[1][2][t] + red[1][3][t];
    }
}

// ============ P3: re-read z2, recompute z3, aggregate over l ============
// grid 2048 (one block per (b,k) band of 256 rows). wave = 64 rows (2 iters of 32).
__global__ __launch_bounds__(256) void pair_stage3(
    const __bf16* __restrict__ Z,
    const float* __restrict__ a2, const float* __restrict__ c2,
    const __bf16* __restrict__ W3t,
    const float* __restrict__ a3, const float* __restrict__ c3,
    const float* __restrict__ Wagg, const float* __restrict__ bagg,
    float* __restrict__ xagg)
{
    __shared__ __align__(16) char wlds[32768];
    __shared__ float red[4][128];

    int bk = blockIdx.x;
    int t = threadIdx.x, lane = t & 63, wave = t >> 6;
    int cl = lane & 15, kg = lane >> 4;

    {
        int fcs = t & 15, rs = t >> 4;
#pragma unroll
        for (int i = 0; i < 8; ++i) {
            int row = rs + i * 16;
            bf16x8 w = *reinterpret_cast<const bf16x8*>(W3t + row * 128 + fcs * 8);
            int byte = row * 256 + ((fcs * 16) ^ ((row & 7) << 4));
            *reinterpret_cast<bf16x8*>(wlds + byte) = w;
        }
    }
    __syncthreads();

    float ag[8][4] = {};

#pragma unroll
    for (int it = 0; it < 2; ++it) {
        size_t row0 = (size_t)bk * 256 + wave * 64 + it * 32;
        f32x4 acc[2][8] = {};
#pragma unroll
        for (int kk = 0; kk < 4; ++kk) {
            int ko = kk * 32 + kg * 8;
            f32x4 a2l = *reinterpret_cast<const f32x4*>(a2 + ko);
            f32x4 a2h = *reinterpret_cast<const f32x4*>(a2 + ko + 4);
            f32x4 c2l = *reinterpret_cast<const f32x4*>(c2 + ko);
            f32x4 c2h = *reinterpret_cast<const f32x4*>(c2 + ko + 4);
            bf16x8 Af[2];
#pragma unroll
            for (int m = 0; m < 2; ++m) {
                bf16x8 zv = *reinterpret_cast<const bf16x8*>(Z + (row0 + m * 16 + cl) * 128 + ko);
#pragma unroll
                for (int j = 0; j < 4; ++j) {
                    Af[m][j]     = (__bf16)fmaxf(a2l[j] * (float)zv[j] + c2l[j], 0.f);
                    Af[m][j + 4] = (__bf16)fmaxf(a2h[j] * (float)zv[j + 4] + c2h[j], 0.f);
                }
            }
#pragma unroll
            for (int n = 0; n < 8; ++n) {
                int r = n * 16 + cl;
                int byte = r * 256 + (((kk * 4 + kg) * 16) ^ ((cl & 7) << 4));
                bf16x8 Bf = *reinterpret_cast<const bf16x8*>(wlds + byte);
#pragma unroll
                for (int m = 0; m < 2; ++m)
                    acc[m][n] = __builtin_amdgcn_mfma_f32_16x16x32_bf16(Bf, Af[m], acc[m][n], 0, 0, 0);
            }
        }
        // aggregate: ag[col] += w[l] * relu(a3*z3 + c3)
        int lb = wave * 64 + it * 32;
        float w0 = Wagg[lb + cl];
        float w1 = Wagg[lb + 16 + cl];
#pragma unroll
        for (int n = 0; n < 8; ++n) {
            f32x4 a3v = *reinterpret_cast<const f32x4*>(a3 + n * 16 + kg * 4);
            f32x4 c3v = *reinterpret_cast<const f32x4*>(c3 + n * 16 + kg * 4);
#pragma unroll
            for (int r = 0; r < 4; ++r) {
                ag[n][r] += w0 * fmaxf(a3v[r] * acc[0][n][r] + c3v[r], 0.f)
                          + w1 * fmaxf(a3v[r] * acc[1][n][r] + c3v[r], 0.f);
            }
        }
    }

    // reduce over cl lanes, then across waves
#pragma unroll
    for (int n = 0; n < 8; ++n) {
#pragma unroll
        for (int r = 0; r < 4; ++r) {
            float v = ag[n][r];
            v += __shfl_xor(v, 1); v += __shfl_xor(v, 2);
            v += __shfl_xor(v, 4); v += __shfl_xor(v, 8);
            if (cl == 0) red[wave][n * 16 + kg * 4 + r] = v;
        }
    }
    __syncthreads();
    if (t < 128)
        xagg[(size_t)bk * 128 + t] = red[0][t] + red[1][t] + red[2][t] + red[3][t] + bagg[0];
}

// ---------------- deterministic BN finalize: one block per channel ----------------
__global__ void finalize_bn(const float* __restrict__ ps, const float* __restrict__ pq,
                            int nblk, float inv_count,
                            const float* __restrict__ gamma, const float* __restrict__ beta,
                            float* __restrict__ a, float* __restrict__ c)
{
    __shared__ float rs[256], rq[256];
    int f = blockIdx.x, t = threadIdx.x;
    float s = 0, q = 0;
    for (int i = t; i < nblk; i += 256) {
        s += ps[(size_t)i * 128 + f];
        q += pq[(size_t)i * 128 + f];
    }
    rs[t] = s; rq[t] = q;
    __syncthreads();
    for (int st = 128; st > 0; st >>= 1) {
        if (t < st) { rs[t] += rs[t + st]; rq[t] += rq[t + st]; }
        __syncthreads();
    }
    if (t == 0) {
        float mean = rs[0] * inv_count;
        float var = rq[0] * inv_count - mean * mean;
        float av = gamma[f] * rsqrtf(var + 1e-5f);
        a[f] = av;
        c[f] = beta[f] - av * mean;
    }
}

// ---------------- tail GEMM (2048x128 @ 128x128) with optional BN+relu on input ----------------
__global__ void tail_gemm(const float* __restrict__ X,
                          const float* __restrict__ aIn, const float* __restrict__ cIn, int relu_in,
                          const float* __restrict__ W, const float* __restrict__ bias,
                          float* __restrict__ Y, float* __restrict__ ps, float* __restrict__ pq)
{
    __shared__ float xs[2048];
    __shared__ float rsum[256];
    int blk = blockIdx.x, t = threadIdx.x;
    for (int i = t; i < 2048; i += 256) {
        float v = X[(size_t)blk * 2048 + i];
        if (relu_in) { int f = i & 127; v = fmaxf(aIn[f] * v + cIn[f], 0.f); }
        xs[i] = v;
    }
    __syncthreads();
    int col = t & 127, hf = t >> 7;
    float bv = bias[col];
    float acc[8];
#pragma unroll
    for (int r = 0; r < 8; ++r) acc[r] = bv;
    for (int k = 0; k < 128; ++k) {
        float w = W[k * 128 + col];
#pragma unroll
        for (int r = 0; r < 8; ++r) acc[r] += xs[(hf * 8 + r) * 128 + k] * w;
    }
    float s = 0, q = 0;
#pragma unroll
    for (int r = 0; r < 8; ++r) {
        Y[((size_t)blk * 16 + hf * 8 + r) * 128 + col] = acc[r];
        s += acc[r]; q += acc[r] * acc[r];
    }
    rsum[t] = s; __syncthreads();
    if (hf == 0) ps[(size_t)blk * 128 + col] = rsum[col] + rsum[128 + col];
    __syncthreads();
    rsum[t] = q; __syncthreads();
    if (hf == 0) pq[(size_t)blk * 128 + col] = rsum[col] + rsum[128 + col];
}

// ---------------- final layer + transpose to (b, f, d, d) ----------------
__global__ void tail_out(const float* __restrict__ Y2,
                         const float* __restrict__ ao, const float* __restrict__ co,
                         const float* __restrict__ Wo3, const float* __restrict__ bo3,
                         float* __restrict__ out)
{
    __shared__ float xs[2048];
    int blk = blockIdx.x, t = threadIdx.x;
    for (int i = t; i < 2048; i += 256) {
        int f = i & 127;
        xs[i] = fmaxf(ao[f] * Y2[(size_t)blk * 2048 + i] + co[f], 0.f);
    }
    __syncthreads();
    int col = t & 15, r = t >> 4;      // 16 rows x 16 out-channels
    float acc = bo3[col];
    for (int k = 0; k < 128; ++k) acc += xs[r * 128 + k] * Wo3[k * 16 + col];
    int grow = blk * 16 + r;           // b*256 + l
    int b = grow >> 8, l = grow & 255;
    out[((size_t)b * 16 + col) * 256 + l] = acc;
}

extern "C" void kernel_launch(void* const* d_in, const int* in_sizes, int n_in,
                              void* d_out, int out_size, void* d_ws, size_t ws_size,
                              hipStream_t stream)
{
    const float* x     = (const float*)d_in[0];
    const float* W1a   = (const float*)d_in[1];
    const float* W1b   = (const float*)d_in[2];
    const float* g1g   = (const float*)d_in[4];
    const float* g1b   = (const float*)d_in[5];
    const float* W2    = (const float*)d_in[6];
    const float* g2g   = (const float*)d_in[8];
    const float* g2b   = (const float*)d_in[9];
    const float* W3    = (const float*)d_in[10];
    const float* g3g   = (const float*)d_in[12];
    const float* g3b   = (const float*)d_in[13];
    const float* Wagg  = (const float*)d_in[14];
    const float* bagg  = (const float*)d_in[15];
    const float* Wf    = (const float*)d_in[16];
    const float* bf_   = (const float*)d_in[17];
    const float* fg    = (const float*)d_in[18];
    const float* fb    = (const float*)d_in[19];
    const float* Wo2   = (const float*)d_in[20];
    const float* bo2   = (const float*)d_in[21];
    const float* og    = (const float*)d_in[22];
    const float* ob    = (const float*)d_in[23];
    const float* Wo3   = (const float*)d_in[24];
    const float* bo3   = (const float*)d_in[25];
    const float* coord = (const float*)d_in[26];

    char* ws = (char*)d_ws;
    float*  HI   = (float*)(ws + HI_OFF);
    float*  HJ   = (float*)(ws + HJ_OFF);
    float*  HIS  = (float*)(ws + HIS_OFF);
    float*  QV   = (float*)(ws + QV_OFF);
    __bf16* Z    = (__bf16*)(ws + Z_OFF);
    float*  PS   = (float*)(ws + PS_OFF);
    float*  PQ   = (float*)(ws + PQ_OFF);
    float*  S1I  = (float*)(ws + S1I_OFF);
    float*  S2I  = (float*)(ws + S2I_OFF);
    float*  S1J  = (float*)(ws + S1J_OFF);
    float*  S2J  = (float*)(ws + S2J_OFF);
    float*  A1   = (float*)(ws + A1_OFF);
    float*  D1   = (float*)(ws + D1_OFF);
    float*  A2   = (float*)(ws + A2_OFF);
    float*  C2   = (float*)(ws + C2_OFF);
    float*  A3   = (float*)(ws + A3_OFF);
    float*  C3   = (float*)(ws + C3_OFF);
    float*  AF   = (float*)(ws + AF_OFF);
    float*  CF   = (float*)(ws + CF_OFF);
    float*  AO   = (float*)(ws + AO_OFF);
    float*  CO   = (float*)(ws + CO_OFF);
    __bf16* W2T  = (__bf16*)(ws + W2T_OFF);
    __bf16* W3T  = (__bf16*)(ws + W3T_OFF);
    float*  XAGG = (float*)(ws + XAGG_OFF);
    float*  Y1   = (float*)(ws + Y1_OFF);
    float*  Y2   = (float*)(ws + Y2_OFF);
    float*  TPS  = (float*)(ws + TPS_OFF);
    float*  TPQ  = (float*)(ws + TPQ_OFF);

    build_h<<<2048, 128, 0, stream>>>(x, coord, W1a, W1b, HI, HJ);
    stats1<<<64, 128, 0, stream>>>(HI, HJ, S1I, S2I, S1J, S2J);
    bn1_finalize<<<1, 128, 0, stream>>>(S1I, S2I, S1J, S2J, g1g, g1b, A1, D1);
    transpose_w<<<128, 128, 0, stream>>>(W2, W3, W2T, W3T);
    scale_h<<<2048, 128, 0, stream>>>(HI, HJ, A1, D1, HIS, QV);

    pair_stage1<<<4096, 256, 0, stream>>>(HIS, QV, W2T, Z, PS, PQ);
    finalize_bn<<<128, 256, 0, stream>>>(PS, PQ, 4096, 1.f / 524288.f, g2g, g2b, A2, C2);

    pair_stage2<<<4096, 256, 0, stream>>>(Z, A2, C2, W3T, PS, PQ);
    finalize_bn<<<128, 256, 0, stream>>>(PS, PQ, 4096, 1.f / 524288.f, g3g, g3b, A3, C3);

    pair_stage3<<<2048, 256, 0, stream>>>(Z, A2, C2, W3T, A3, C3, Wagg, bagg, XAGG);

    tail_gemm<<<128, 256, 0, stream>>>(XAGG, A1, D1, 0, Wf, bf_, Y1, TPS, TPQ);
    finalize_bn<<<128, 256, 0, stream>>>(TPS, TPQ, 128, 1.f / 2048.f, fg, fb, AF, CF);

    tail_gemm<<<128, 256, 0, stream>>>(Y1, AF, CF, 1, Wo2, bo2, Y2, TPS, TPQ);
    finalize_bn<<<128, 256, 0, stream>>>(TPS, TPQ, 128, 1.f / 2048.f, og, ob, AO, CO);

    tail_out<<<128, 256, 0, stream>>>(Y2, AO, CO, Wo3, bo3, (float*)d_out);

    (void)in_sizes; (void)n_in; (void)out_size; (void)ws_size;
}